// Round 1
// baseline (996.124 us; speedup 1.0000x reference)
//
#include <hip/hip_runtime.h>

typedef unsigned long long u64;
typedef unsigned int u32;
typedef unsigned short u16;
typedef float f32x4 __attribute__((ext_vector_type(4)));
typedef __bf16 bf16x8 __attribute__((ext_vector_type(8)));

#define N_TOK 32768

// ---------- helpers ----------
__device__ inline u16 f2bf(float f){
  u32 x = __float_as_uint(f);
  u32 r = x + 0x7FFFu + ((x >> 16) & 1u);
  return (u16)(r >> 16);
}

__device__ inline f32x4 mfma16(bf16x8 a, bf16x8 b, f32x4 c){
  return __builtin_amdgcn_mfma_f32_16x16x32_bf16(a, b, c, 0, 0, 0);
}

// rolled-perm lookup: token index at sorted position j (with shifted-window roll)
__device__ inline u32 rp_idx(const u64* __restrict__ keys, int j, int shift){
  return (u32)(keys[(j + N_TOK - shift) & (N_TOK - 1)] & 0xFFFFull);
}

__device__ inline float gelu_tanh(float x){
  float u = 0.7978845608028654f * (x + 0.044715f * x * x * x);
  float e = __expf(2.0f * u);
  return 0.5f * x * (2.0f - 2.0f / (e + 1.0f));   // 0.5x(1+tanh(u)), inf-safe
}

__device__ inline u32 part1by2(u32 v){
  v &= 0x3FFu;
  v = (v | (v << 16)) & 0x030000FFu;
  v = (v | (v << 8))  & 0x0300F00Fu;
  v = (v | (v << 4))  & 0x030C30C3u;
  v = (v | (v << 2))  & 0x09249249u;
  return v;
}

// ---------- coords min/max (single block) ----------
__global__ void __launch_bounds__(1024) minmax_kernel(const float* __restrict__ coords,
                                                      float* __restrict__ cmm){
  float mn[3] = {1e30f,1e30f,1e30f}, mx[3] = {-1e30f,-1e30f,-1e30f};
  for (int t = threadIdx.x; t < N_TOK; t += 1024){
    #pragma unroll
    for (int a = 0; a < 3; ++a){
      float v = coords[t*3 + a];
      mn[a] = fminf(mn[a], v); mx[a] = fmaxf(mx[a], v);
    }
  }
  #pragma unroll
  for (int a = 0; a < 3; ++a){
    for (int m = 1; m < 64; m <<= 1){
      mn[a] = fminf(mn[a], __shfl_xor(mn[a], m));
      mx[a] = fmaxf(mx[a], __shfl_xor(mx[a], m));
    }
  }
  __shared__ float smn[16][3], smx[16][3];
  int w = threadIdx.x >> 6, lane = threadIdx.x & 63;
  if (lane == 0){
    #pragma unroll
    for (int a = 0; a < 3; ++a){ smn[w][a] = mn[a]; smx[w][a] = mx[a]; }
  }
  __syncthreads();
  if (threadIdx.x == 0){
    for (int i = 1; i < 16; ++i)
      for (int a = 0; a < 3; ++a){
        smn[0][a] = fminf(smn[0][a], smn[i][a]);
        smx[0][a] = fmaxf(smx[0][a], smx[i][a]);
      }
    for (int a = 0; a < 3; ++a){ cmm[a] = smn[0][a]; cmm[3+a] = smx[0][a]; }
  }
}

// ---------- weight convert + transpose: W[K][Nn] f32 -> Wt[Nn][K] bf16 ----------
__global__ void __launch_bounds__(256) wprep_kernel(const float* __restrict__ src,
                                                    u16* __restrict__ dst, int K, int Nn){
  int layer = blockIdx.y;
  src += (size_t)layer * K * Nn;
  dst += (size_t)layer * K * Nn;
  int ntx = Nn >> 5;
  int tk = blockIdx.x / ntx, tn = blockIdx.x % ntx;
  __shared__ float tile[32][33];
  int r = threadIdx.x >> 5, c = threadIdx.x & 31;
  for (int rr = r; rr < 32; rr += 8)
    tile[rr][c] = src[(size_t)(tk*32 + rr) * Nn + tn*32 + c];
  __syncthreads();
  for (int rr = r; rr < 32; rr += 8)
    dst[(size_t)(tn*32 + rr) * K + tk*32 + c] = f2bf(tile[c][rr]);
}

// ---------- morton keys ----------
__global__ void __launch_bounds__(256) codes_kernel(const float* __restrict__ coords,
                                                    const float* __restrict__ cmm,
                                                    u64* __restrict__ keys, int layer){
  int t = blockIdx.x * 256 + threadIdx.x;
  if (t >= N_TOK) return;
  u32 code = 0;
  #pragma unroll
  for (int j = 0; j < 3; ++j){
    int ax = (j + layer) % 3;
    float c = coords[t*3 + ax];
    float mn = cmm[ax], mx = cmm[3 + ax];
    float v = (c - mn) / (mx - mn + 1e-9f) * 1023.0f;  // matches jax arithmetic
    int q = (int)v;
    q = q < 0 ? 0 : (q > 1023 ? 1023 : q);
    code |= part1by2((u32)q) << j;
  }
  keys[t] = ((u64)code << 16) | (u32)t;  // idx in low bits -> stable
}

// ---------- bitonic sort (ascending, 32768 u64) ----------
__global__ void __launch_bounds__(256) bitonic_local_sort(u64* __restrict__ keys){
  __shared__ u64 s[4096];
  int base = blockIdx.x * 4096;
  for (int i = threadIdx.x; i < 4096; i += 256) s[i] = keys[base + i];
  __syncthreads();
  for (int k = 2; k <= 4096; k <<= 1){
    for (int j = k >> 1; j > 0; j >>= 1){
      for (int p = threadIdx.x; p < 2048; p += 256){
        int i = ((p & ~(j-1)) << 1) | (p & (j-1));
        int l = i + j;
        bool asc = (((base + i) & k) == 0);
        u64 a = s[i], b = s[l];
        if ((a > b) == asc){ s[i] = b; s[l] = a; }
      }
      __syncthreads();
    }
  }
  for (int i = threadIdx.x; i < 4096; i += 256) keys[base + i] = s[i];
}

__global__ void __launch_bounds__(256) bitonic_global_step(u64* __restrict__ keys, int j, int k){
  int p = blockIdx.x * 256 + threadIdx.x;
  int i = ((p & ~(j-1)) << 1) | (p & (j-1));
  int l = i + j;
  bool asc = ((i & k) == 0);
  u64 a = keys[i], b = keys[l];
  if ((a > b) == asc){ keys[i] = b; keys[l] = a; }
}

__global__ void __launch_bounds__(256) bitonic_local_merge(u64* __restrict__ keys, int k){
  __shared__ u64 s[4096];
  int base = blockIdx.x * 4096;
  for (int i = threadIdx.x; i < 4096; i += 256) s[i] = keys[base + i];
  __syncthreads();
  for (int j = 2048; j > 0; j >>= 1){
    for (int p = threadIdx.x; p < 2048; p += 256){
      int i = ((p & ~(j-1)) << 1) | (p & (j-1));
      int l = i + j;
      bool asc = (((base + i) & k) == 0);
      u64 a = s[i], b = s[l];
      if ((a > b) == asc){ s[i] = b; s[l] = a; }
    }
    __syncthreads();
  }
  for (int i = threadIdx.x; i < 4096; i += 256) keys[base + i] = s[i];
}

// ---------- gather + LN1 + positional projection d = c.w_pos ----------
__global__ void __launch_bounds__(256) gather_ln1_kernel(
    const float* __restrict__ xin, const float* __restrict__ coords,
    const u64* __restrict__ keys, int shift,
    const float* __restrict__ g1, const float* __restrict__ b1,
    const float* __restrict__ wpos,           // [3][8] for this layer
    float* __restrict__ dproj, u16* __restrict__ h){
  int w = threadIdx.x >> 6, lane = threadIdx.x & 63;
  int j = blockIdx.x * 4 + w;
  u32 src = rp_idx(keys, j, shift);
  float4 v = ((const float4*)xin)[(size_t)src * 64 + lane];
  float s = v.x + v.y + v.z + v.w;
  for (int m = 1; m < 64; m <<= 1) s += __shfl_xor(s, m);
  float mean = s * (1.0f / 256.0f);
  float dx = v.x - mean, dy = v.y - mean, dz = v.z - mean, dw = v.w - mean;
  float q = dx*dx + dy*dy + dz*dz + dw*dw;
  for (int m = 1; m < 64; m <<= 1) q += __shfl_xor(q, m);
  float rs = rsqrtf(q * (1.0f / 256.0f) + 1e-5f);
  int c0 = lane * 4;
  u16 h0 = f2bf(dx * rs * g1[c0+0] + b1[c0+0]);
  u16 h1 = f2bf(dy * rs * g1[c0+1] + b1[c0+1]);
  u16 h2 = f2bf(dz * rs * g1[c0+2] + b1[c0+2]);
  u16 h3 = f2bf(dw * rs * g1[c0+3] + b1[c0+3]);
  uint2 pk; pk.x = (u32)h0 | ((u32)h1 << 16); pk.y = (u32)h2 | ((u32)h3 << 16);
  *(uint2*)&h[(size_t)j * 256 + c0] = pk;
  if (lane < 8){
    float acc = 0.0f;
    #pragma unroll
    for (int c = 0; c < 3; ++c) acc += coords[(size_t)src*3 + c] * wpos[c*8 + lane];
    dproj[(size_t)j * 8 + lane] = acc;
  }
}

// ---------- LN (bf16 out) ----------
__global__ void __launch_bounds__(256) ln_bf16_kernel(const float* __restrict__ xin,
    const float* __restrict__ g, const float* __restrict__ b, u16* __restrict__ out){
  int w = threadIdx.x >> 6, lane = threadIdx.x & 63;
  int j = blockIdx.x * 4 + w;
  float4 v = ((const float4*)xin)[(size_t)j * 64 + lane];
  float s = v.x + v.y + v.z + v.w;
  for (int m = 1; m < 64; m <<= 1) s += __shfl_xor(s, m);
  float mean = s * (1.0f / 256.0f);
  float dx = v.x - mean, dy = v.y - mean, dz = v.z - mean, dw = v.w - mean;
  float q = dx*dx + dy*dy + dz*dz + dw*dw;
  for (int m = 1; m < 64; m <<= 1) q += __shfl_xor(q, m);
  float rs = rsqrtf(q * (1.0f / 256.0f) + 1e-5f);
  int c0 = lane * 4;
  u16 h0 = f2bf(dx * rs * g[c0+0] + b[c0+0]);
  u16 h1 = f2bf(dy * rs * g[c0+1] + b[c0+1]);
  u16 h2 = f2bf(dz * rs * g[c0+2] + b[c0+2]);
  u16 h3 = f2bf(dw * rs * g[c0+3] + b[c0+3]);
  uint2 pk; pk.x = (u32)h0 | ((u32)h1 << 16); pk.y = (u32)h2 | ((u32)h3 << 16);
  *(uint2*)&out[(size_t)j * 256 + c0] = pk;
}

// ---------- final LN (f32 out) ----------
__global__ void __launch_bounds__(256) ln_final_kernel(const float* __restrict__ xin,
    const float* __restrict__ g, const float* __restrict__ b, float* __restrict__ out){
  int w = threadIdx.x >> 6, lane = threadIdx.x & 63;
  int j = blockIdx.x * 4 + w;
  float4 v = ((const float4*)xin)[(size_t)j * 64 + lane];
  float s = v.x + v.y + v.z + v.w;
  for (int m = 1; m < 64; m <<= 1) s += __shfl_xor(s, m);
  float mean = s * (1.0f / 256.0f);
  float dx = v.x - mean, dy = v.y - mean, dz = v.z - mean, dw = v.w - mean;
  float q = dx*dx + dy*dy + dz*dz + dw*dw;
  for (int m = 1; m < 64; m <<= 1) q += __shfl_xor(q, m);
  float rs = rsqrtf(q * (1.0f / 256.0f) + 1e-5f);
  int c0 = lane * 4;
  float4 o;
  o.x = dx * rs * g[c0+0] + b[c0+0];
  o.y = dy * rs * g[c0+1] + b[c0+1];
  o.z = dz * rs * g[c0+2] + b[c0+2];
  o.w = dw * rs * g[c0+3] + b[c0+3];
  ((float4*)out)[(size_t)j * 64 + lane] = o;
}

// ---------- GEMM: C[32768,Nn] = A[32768,K] @ Wt^T + bias (Wt is [Nn][K] bf16) ----------
// EPI 0: bf16 out. 1: gelu->bf16 out. 2 (proj): f32 out = res[gather(row)] + v.
// 3 (fc2): f32 out[scatter(row)] = res[row] + v.   (EPI 2/3 assume Nn outputs stride 256)
template<int EPI>
__global__ void __launch_bounds__(256) gemm_kernel(
    const u16* __restrict__ A, const u16* __restrict__ Wt,
    const float* __restrict__ bias, int K, int Nn,
    u16* __restrict__ outb, float* __restrict__ outf,
    const float* __restrict__ res, const u64* __restrict__ keys, int shift){
  __shared__ u16 As[64 * 40];
  __shared__ u16 Ws[64 * 40];
  int m0 = blockIdx.x * 64;
  int n0 = blockIdx.y * 64;
  int tid = threadIdx.x;
  int w = tid >> 6, lane = tid & 63, lc = lane & 15, g = lane >> 4;
  f32x4 acc[4];
  #pragma unroll
  for (int c = 0; c < 4; ++c) acc[c] = (f32x4){0.f,0.f,0.f,0.f};
  int r_st = tid >> 2, ch = (tid & 3) * 8;
  const u16* Ag = A  + (size_t)(m0 + r_st) * K + ch;
  const u16* Wg = Wt + (size_t)(n0 + r_st) * K + ch;
  for (int kk = 0; kk < K; kk += 32){
    *(uint4*)&As[r_st*40 + ch] = *(const uint4*)(Ag + kk);
    *(uint4*)&Ws[r_st*40 + ch] = *(const uint4*)(Wg + kk);
    __syncthreads();
    bf16x8 af = *(const bf16x8*)&As[(w*16 + lc)*40 + g*8];
    #pragma unroll
    for (int c = 0; c < 4; ++c){
      bf16x8 bf = *(const bf16x8*)&Ws[(c*16 + lc)*40 + g*8];
      acc[c] = mfma16(af, bf, acc[c]);
    }
    __syncthreads();
  }
  #pragma unroll
  for (int c = 0; c < 4; ++c){
    int col = n0 + c*16 + lc;
    float bv = bias[col];
    #pragma unroll
    for (int r = 0; r < 4; ++r){
      int row = m0 + w*16 + g*4 + r;
      float v = acc[c][r] + bv;
      if constexpr (EPI == 0){
        outb[(size_t)row * Nn + col] = f2bf(v);
      } else if constexpr (EPI == 1){
        outb[(size_t)row * Nn + col] = f2bf(gelu_tanh(v));
      } else if constexpr (EPI == 2){
        u32 src = rp_idx(keys, row, shift);
        outf[(size_t)row * 256 + col] = res[(size_t)src * 256 + col] + v;
      } else {
        u32 dst = rp_idx(keys, row, shift);
        outf[(size_t)dst * 256 + col] = res[(size_t)row * 256 + col] + v;
      }
    }
  }
}

// ---------- attention: one block per (patch, head) ----------
// qkvb bf16 [32768][768]; per-key bias scalar d subtracted before softmax.
#define ATTN_LDS (512*40*2 + 32*520*2 + 512*4 + 4*16*40*2)
__global__ void __launch_bounds__(256) attn_kernel(
    const u16* __restrict__ qkvb, const float* __restrict__ dproj,
    u16* __restrict__ o){
  extern __shared__ char smem[];
  u16* Kl = (u16*)smem;                                 // [512][40]
  u16* Vt = (u16*)(smem + 512*40*2);                    // [32][520] (transposed V)
  float* dl = (float*)(smem + 512*40*2 + 32*520*2);     // [512]
  u16* Pl = (u16*)(smem + 512*40*2 + 32*520*2 + 512*4); // [4][16][40]
  int m = blockIdx.x >> 3;
  int h = blockIdx.x & 7;
  int base = m * 512;
  int tid = threadIdx.x, w = tid >> 6, lane = tid & 63, lc = lane & 15, g = lane >> 4;
  for (int i = tid; i < 512*4; i += 256){
    int row = i >> 2, ch = (i & 3) * 8;
    *(uint4*)&Kl[row*40 + ch] = *(const uint4*)&qkvb[(size_t)(base+row)*768 + 256 + h*32 + ch];
  }
  for (int i = tid; i < 512*4; i += 256){
    int row = i >> 2, d0 = (i & 3) * 8;
    uint4 vv = *(const uint4*)&qkvb[(size_t)(base+row)*768 + 512 + h*32 + d0];
    const u16* pv = (const u16*)&vv;
    #pragma unroll
    for (int e = 0; e < 8; ++e) Vt[(d0+e)*520 + row] = pv[e];
  }
  for (int i = tid; i < 512; i += 256) dl[i] = dproj[(size_t)(base+i)*8 + h];
  __syncthreads();
  u16* Pw = Pl + w * 16 * 40;
  const float SC = 0.17677669529663687f;  // 1/sqrt(32)
  const f32x4 zf = {0.f,0.f,0.f,0.f};
  for (int t = 0; t < 8; ++t){
    int q0 = w*128 + t*16;
    bf16x8 qf = *(const bf16x8*)&qkvb[(size_t)(base + q0 + lc)*768 + h*32 + g*8];
    f32x4 o0 = zf, o1 = zf;
    float m4[4] = {-1e30f,-1e30f,-1e30f,-1e30f};
    float l4[4] = {0.f,0.f,0.f,0.f};
    for (int kt = 0; kt < 16; ++kt){
      int kb = kt * 32;
      bf16x8 k0 = *(const bf16x8*)&Kl[(kb + lc)*40 + g*8];
      bf16x8 k1 = *(const bf16x8*)&Kl[(kb + 16 + lc)*40 + g*8];
      f32x4 s0 = mfma16(qf, k0, zf);
      f32x4 s1 = mfma16(qf, k1, zf);
      float d0 = dl[kb + lc], d1 = dl[kb + 16 + lc];
      float p0[4], p1[4];
      #pragma unroll
      for (int r = 0; r < 4; ++r){
        float a0 = s0[r]*SC - d0;
        float a1 = s1[r]*SC - d1;
        float v = fmaxf(a0, a1);
        v = fmaxf(v, __shfl_xor(v, 1));
        v = fmaxf(v, __shfl_xor(v, 2));
        v = fmaxf(v, __shfl_xor(v, 4));
        v = fmaxf(v, __shfl_xor(v, 8));
        float mn = fmaxf(m4[r], v);
        float sco = __expf(m4[r] - mn);
        m4[r] = mn;
        p0[r] = __expf(a0 - mn);
        p1[r] = __expf(a1 - mn);
        float rs = p0[r] + p1[r];
        rs += __shfl_xor(rs, 1);
        rs += __shfl_xor(rs, 2);
        rs += __shfl_xor(rs, 4);
        rs += __shfl_xor(rs, 8);
        l4[r] = l4[r]*sco + rs;
        o0[r] *= sco; o1[r] *= sco;
        Pw[(g*4 + r)*40 + lc]      = f2bf(p0[r]);
        Pw[(g*4 + r)*40 + 16 + lc] = f2bf(p1[r]);
      }
      __threadfence_block();  // order P writes before re-layout read (wave-private)
      bf16x8 pf = *(const bf16x8*)&Pw[lc*40 + g*8];
      bf16x8 v0 = *(const bf16x8*)&Vt[lc*520 + kb + g*8];
      bf16x8 v1 = *(const bf16x8*)&Vt[(16 + lc)*520 + kb + g*8];
      __threadfence_block();  // keep next iter's P writes after these reads
      o0 = mfma16(pf, v0, o0);
      o1 = mfma16(pf, v1, o1);
    }
    #pragma unroll
    for (int r = 0; r < 4; ++r){
      float inv = 1.0f / l4[r];
      size_t tok = (size_t)(base + q0 + g*4 + r);
      o[tok*256 + h*32 + lc]      = f2bf(o0[r] * inv);
      o[tok*256 + h*32 + 16 + lc] = f2bf(o1[r] * inv);
    }
  }
}

// ---------- host ----------
extern "C" void kernel_launch(void* const* d_in, const int* in_sizes, int n_in,
                              void* d_out, int out_size, void* d_ws, size_t ws_size,
                              hipStream_t stream){
  const float* x      = (const float*)d_in[0];
  const float* coords = (const float*)d_in[1];
  const float* ln1_g  = (const float*)d_in[2];
  const float* ln1_b  = (const float*)d_in[3];
  const float* w_qkv  = (const float*)d_in[4];
  const float* b_qkv  = (const float*)d_in[5];
  const float* w_proj = (const float*)d_in[6];
  const float* b_proj = (const float*)d_in[7];
  const float* w_pos  = (const float*)d_in[8];
  // d_in[9] = b_pos: cancels in softmax (row-constant), unused
  const float* ln2_g  = (const float*)d_in[10];
  const float* ln2_b  = (const float*)d_in[11];
  const float* w_fc1  = (const float*)d_in[12];
  const float* b_fc1  = (const float*)d_in[13];
  const float* w_fc2  = (const float*)d_in[14];
  const float* b_fc2  = (const float*)d_in[15];
  const float* norm_g = (const float*)d_in[16];
  const float* norm_b = (const float*)d_in[17];
  float* outp = (float*)d_out;

  char* ws = (char*)d_ws;
  size_t off = 0;
  auto alloc = [&](size_t bytes) -> void* {
    void* p = ws + off;
    off += (bytes + 255) & ~(size_t)255;
    return p;
  };
  u64*   keys   = (u64*)  alloc((size_t)N_TOK * 8);
  float* cmm    = (float*)alloc(256);
  float* dproj  = (float*)alloc((size_t)N_TOK * 8 * 4);
  u16*   h      = (u16*)  alloc((size_t)N_TOK * 256 * 2);   // also reused as h2
  u16*   qkvb   = (u16*)  alloc((size_t)N_TOK * 768 * 2);   // also reused as layer-2 output (f32)
  float* x2     = (float*)alloc((size_t)N_TOK * 256 * 4);
  u16*   t      = (u16*)  alloc((size_t)N_TOK * 1024 * 2);  // front 1/4 also reused as attn out o
  float* xA     = (float*)alloc((size_t)N_TOK * 256 * 4);
  u16*   wtqkv  = (u16*)  alloc((size_t)2 * 256 * 768 * 2);
  u16*   wtproj = (u16*)  alloc((size_t)2 * 256 * 256 * 2);
  u16*   wtfc1  = (u16*)  alloc((size_t)2 * 256 * 1024 * 2);
  u16*   wtfc2  = (u16*)  alloc((size_t)2 * 1024 * 256 * 2);
  u16*   o      = t;            // alias: o dead before fc1 writes t
  float* xB     = (float*)qkvb; // alias: layer-2 qkv dead before fc2 writes xB
  (void)in_sizes; (void)n_in; (void)out_size; (void)ws_size;

  minmax_kernel<<<1, 1024, 0, stream>>>(coords, cmm);
  wprep_kernel<<<dim3(8*24, 2),  256, 0, stream>>>(w_qkv,  wtqkv,  256, 768);
  wprep_kernel<<<dim3(8*8, 2),   256, 0, stream>>>(w_proj, wtproj, 256, 256);
  wprep_kernel<<<dim3(8*32, 2),  256, 0, stream>>>(w_fc1,  wtfc1,  256, 1024);
  wprep_kernel<<<dim3(32*8, 2),  256, 0, stream>>>(w_fc2,  wtfc2,  1024, 256);

  for (int layer = 0; layer < 2; ++layer){
    int shift = (layer & 1) ? 256 : 0;
    const float* xin = (layer == 0) ? x : xA;
    float* xout = (layer == 0) ? xA : xB;

    codes_kernel<<<128, 256, 0, stream>>>(coords, cmm, keys, layer);
    bitonic_local_sort<<<8, 256, 0, stream>>>(keys);
    for (int k = 8192; k <= 32768; k <<= 1){
      for (int j = k >> 1; j >= 4096; j >>= 1)
        bitonic_global_step<<<64, 256, 0, stream>>>(keys, j, k);
      bitonic_local_merge<<<8, 256, 0, stream>>>(keys, k);
    }
    gather_ln1_kernel<<<8192, 256, 0, stream>>>(xin, coords, keys, shift,
        ln1_g + layer*256, ln1_b + layer*256, w_pos + layer*24, dproj, h);
    gemm_kernel<0><<<dim3(512, 12), 256, 0, stream>>>(h, wtqkv + (size_t)layer*768*256,
        b_qkv + layer*768, 256, 768, qkvb, nullptr, nullptr, nullptr, 0);
    attn_kernel<<<512, 256, ATTN_LDS, stream>>>(qkvb, dproj, o);
    gemm_kernel<2><<<dim3(512, 4), 256, 0, stream>>>(o, wtproj + (size_t)layer*256*256,
        b_proj + layer*256, 256, 256, nullptr, x2, xin, keys, shift);
    ln_bf16_kernel<<<8192, 256, 0, stream>>>(x2, ln2_g + layer*256, ln2_b + layer*256, h);
    gemm_kernel<1><<<dim3(512, 16), 256, 0, stream>>>(h, wtfc1 + (size_t)layer*1024*256,
        b_fc1 + layer*1024, 256, 1024, t, nullptr, nullptr, nullptr, 0);
    gemm_kernel<3><<<dim3(512, 4), 256, 0, stream>>>(t, wtfc2 + (size_t)layer*256*1024,
        b_fc2 + layer*256, 1024, 256, nullptr, xout, x2, keys, shift);
  }
  ln_final_kernel<<<8192, 256, 0, stream>>>(xB, norm_g, norm_b, outp);
}

// Round 2
// 667.370 us; speedup vs baseline: 1.4926x; 1.4926x over previous
//
#include <hip/hip_runtime.h>

typedef unsigned long long u64;
typedef unsigned int u32;
typedef unsigned short u16;
typedef float f32x4 __attribute__((ext_vector_type(4)));
typedef __bf16 bf16x8 __attribute__((ext_vector_type(8)));

#define N_TOK 32768

// ---------- helpers ----------
__device__ inline u16 f2bf(float f){
  u32 x = __float_as_uint(f);
  u32 r = x + 0x7FFFu + ((x >> 16) & 1u);
  return (u16)(r >> 16);
}

__device__ inline f32x4 mfma16(bf16x8 a, bf16x8 b, f32x4 c){
  return __builtin_amdgcn_mfma_f32_16x16x32_bf16(a, b, c, 0, 0, 0);
}

typedef const __attribute__((address_space(1))) unsigned int* gas_ptr;
typedef __attribute__((address_space(3))) unsigned int* las_ptr;
__device__ inline void gload_lds16(const u16* g, u16* l){
  __builtin_amdgcn_global_load_lds((gas_ptr)g, (las_ptr)l, 16, 0, 0);
}

// rolled-perm lookup: token index at sorted position j (with shifted-window roll)
__device__ inline u32 rp_idx(const u64* __restrict__ keys, int j, int shift){
  return (u32)(keys[(j + N_TOK - shift) & (N_TOK - 1)] & 0xFFFFull);
}

__device__ inline float gelu_tanh(float x){
  float u = 0.7978845608028654f * (x + 0.044715f * x * x * x);
  float e = __expf(2.0f * u);
  return 0.5f * x * (2.0f - 2.0f / (e + 1.0f));   // 0.5x(1+tanh(u)), inf-safe
}

__device__ inline u32 part1by2(u32 v){
  v &= 0x3FFu;
  v = (v | (v << 16)) & 0x030000FFu;
  v = (v | (v << 8))  & 0x0300F00Fu;
  v = (v | (v << 4))  & 0x030C30C3u;
  v = (v | (v << 2))  & 0x09249249u;
  return v;
}

// ---------- coords min/max (single block) ----------
__global__ void __launch_bounds__(1024) minmax_kernel(const float* __restrict__ coords,
                                                      float* __restrict__ cmm){
  float mn[3] = {1e30f,1e30f,1e30f}, mx[3] = {-1e30f,-1e30f,-1e30f};
  for (int t = threadIdx.x; t < N_TOK; t += 1024){
    #pragma unroll
    for (int a = 0; a < 3; ++a){
      float v = coords[t*3 + a];
      mn[a] = fminf(mn[a], v); mx[a] = fmaxf(mx[a], v);
    }
  }
  #pragma unroll
  for (int a = 0; a < 3; ++a){
    for (int m = 1; m < 64; m <<= 1){
      mn[a] = fminf(mn[a], __shfl_xor(mn[a], m));
      mx[a] = fmaxf(mx[a], __shfl_xor(mx[a], m));
    }
  }
  __shared__ float smn[16][3], smx[16][3];
  int w = threadIdx.x >> 6, lane = threadIdx.x & 63;
  if (lane == 0){
    #pragma unroll
    for (int a = 0; a < 3; ++a){ smn[w][a] = mn[a]; smx[w][a] = mx[a]; }
  }
  __syncthreads();
  if (threadIdx.x == 0){
    for (int i = 1; i < 16; ++i)
      for (int a = 0; a < 3; ++a){
        smn[0][a] = fminf(smn[0][a], smn[i][a]);
        smx[0][a] = fmaxf(smx[0][a], smx[i][a]);
      }
    for (int a = 0; a < 3; ++a){ cmm[a] = smn[0][a]; cmm[3+a] = smx[0][a]; }
  }
}

// ---------- weight convert + transpose: W[K][Nn] f32 -> Wt[Nn][K] bf16 ----------
__global__ void __launch_bounds__(256) wprep_kernel(const float* __restrict__ src,
                                                    u16* __restrict__ dst, int K, int Nn){
  int layer = blockIdx.y;
  src += (size_t)layer * K * Nn;
  dst += (size_t)layer * K * Nn;
  int ntx = Nn >> 5;
  int tk = blockIdx.x / ntx, tn = blockIdx.x % ntx;
  __shared__ float tile[32][33];
  int r = threadIdx.x >> 5, c = threadIdx.x & 31;
  for (int rr = r; rr < 32; rr += 8)
    tile[rr][c] = src[(size_t)(tk*32 + rr) * Nn + tn*32 + c];
  __syncthreads();
  for (int rr = r; rr < 32; rr += 8)
    dst[(size_t)(tn*32 + rr) * K + tk*32 + c] = f2bf(tile[c][rr]);
}

// ---------- morton keys, both layers at once: keys[2][N_TOK] ----------
__global__ void __launch_bounds__(256) codes_kernel(const float* __restrict__ coords,
                                                    const float* __restrict__ cmm,
                                                    u64* __restrict__ keys){
  int p = blockIdx.x * 256 + threadIdx.x;   // 0 .. 2*N_TOK
  int layer = p >> 15, t = p & (N_TOK - 1);
  u32 code = 0;
  #pragma unroll
  for (int j = 0; j < 3; ++j){
    int ax = (j + layer) % 3;
    float c = coords[t*3 + ax];
    float mn = cmm[ax], mx = cmm[3 + ax];
    float v = (c - mn) / (mx - mn + 1e-9f) * 1023.0f;  // matches jax arithmetic
    int q = (int)v;
    q = q < 0 ? 0 : (q > 1023 ? 1023 : q);
    code |= part1by2((u32)q) << j;
  }
  keys[p] = ((u64)code << 16) | (u32)t;  // idx in low bits -> stable
}

// ---------- bitonic sort (ascending per 32768-segment, flat [2][N_TOK]) ----------
__global__ void __launch_bounds__(256) bitonic_local_sort(u64* __restrict__ keys){
  __shared__ u64 s[4096];
  int base = blockIdx.x * 4096;
  for (int i = threadIdx.x; i < 4096; i += 256) s[i] = keys[base + i];
  __syncthreads();
  for (int k = 2; k <= 4096; k <<= 1){
    for (int j = k >> 1; j > 0; j >>= 1){
      for (int p = threadIdx.x; p < 2048; p += 256){
        int i = ((p & ~(j-1)) << 1) | (p & (j-1));
        int l = i + j;
        bool asc = ((((base + i) & (N_TOK-1)) & k) == 0);
        u64 a = s[i], b = s[l];
        if ((a > b) == asc){ s[i] = b; s[l] = a; }
      }
      __syncthreads();
    }
  }
  for (int i = threadIdx.x; i < 4096; i += 256) keys[base + i] = s[i];
}

__global__ void __launch_bounds__(256) bitonic_global_step(u64* __restrict__ keys, int j, int k){
  int p = blockIdx.x * 256 + threadIdx.x;   // 2*16384 threads
  int layer = p >> 14, pl = p & 16383;
  int i = ((pl & ~(j-1)) << 1) | (pl & (j-1));
  int l = i + j;
  bool asc = ((i & k & (N_TOK-1)) == 0);
  u64* kp = keys + (layer << 15);
  u64 a = kp[i], b = kp[l];
  if ((a > b) == asc){ kp[i] = b; kp[l] = a; }
}

__global__ void __launch_bounds__(256) bitonic_local_merge(u64* __restrict__ keys, int k){
  __shared__ u64 s[4096];
  int base = blockIdx.x * 4096;
  for (int i = threadIdx.x; i < 4096; i += 256) s[i] = keys[base + i];
  __syncthreads();
  for (int j = 2048; j > 0; j >>= 1){
    for (int p = threadIdx.x; p < 2048; p += 256){
      int i = ((p & ~(j-1)) << 1) | (p & (j-1));
      int l = i + j;
      bool asc = ((((base + i) & (N_TOK-1)) & k) == 0);
      u64 a = s[i], b = s[l];
      if ((a > b) == asc){ s[i] = b; s[l] = a; }
    }
    __syncthreads();
  }
  for (int i = threadIdx.x; i < 4096; i += 256) keys[base + i] = s[i];
}

// ---------- gather + LN1 + positional projection d = c.w_pos ----------
__global__ void __launch_bounds__(256) gather_ln1_kernel(
    const float* __restrict__ xin, const float* __restrict__ coords,
    const u64* __restrict__ keys, int shift,
    const float* __restrict__ g1, const float* __restrict__ b1,
    const float* __restrict__ wpos,           // [3][8] for this layer
    float* __restrict__ dproj, u16* __restrict__ h){
  int w = threadIdx.x >> 6, lane = threadIdx.x & 63;
  int j = blockIdx.x * 4 + w;
  u32 src = rp_idx(keys, j, shift);
  float4 v = ((const float4*)xin)[(size_t)src * 64 + lane];
  float s = v.x + v.y + v.z + v.w;
  for (int m = 1; m < 64; m <<= 1) s += __shfl_xor(s, m);
  float mean = s * (1.0f / 256.0f);
  float dx = v.x - mean, dy = v.y - mean, dz = v.z - mean, dw = v.w - mean;
  float q = dx*dx + dy*dy + dz*dz + dw*dw;
  for (int m = 1; m < 64; m <<= 1) q += __shfl_xor(q, m);
  float rs = rsqrtf(q * (1.0f / 256.0f) + 1e-5f);
  int c0 = lane * 4;
  u16 h0 = f2bf(dx * rs * g1[c0+0] + b1[c0+0]);
  u16 h1 = f2bf(dy * rs * g1[c0+1] + b1[c0+1]);
  u16 h2 = f2bf(dz * rs * g1[c0+2] + b1[c0+2]);
  u16 h3 = f2bf(dw * rs * g1[c0+3] + b1[c0+3]);
  uint2 pk; pk.x = (u32)h0 | ((u32)h1 << 16); pk.y = (u32)h2 | ((u32)h3 << 16);
  *(uint2*)&h[(size_t)j * 256 + c0] = pk;
  if (lane < 8){
    float acc = 0.0f;
    #pragma unroll
    for (int c = 0; c < 3; ++c) acc += coords[(size_t)src*3 + c] * wpos[c*8 + lane];
    dproj[(size_t)j * 8 + lane] = acc;
  }
}

// ---------- LN (bf16 out) ----------
__global__ void __launch_bounds__(256) ln_bf16_kernel(const float* __restrict__ xin,
    const float* __restrict__ g, const float* __restrict__ b, u16* __restrict__ out){
  int w = threadIdx.x >> 6, lane = threadIdx.x & 63;
  int j = blockIdx.x * 4 + w;
  float4 v = ((const float4*)xin)[(size_t)j * 64 + lane];
  float s = v.x + v.y + v.z + v.w;
  for (int m = 1; m < 64; m <<= 1) s += __shfl_xor(s, m);
  float mean = s * (1.0f / 256.0f);
  float dx = v.x - mean, dy = v.y - mean, dz = v.z - mean, dw = v.w - mean;
  float q = dx*dx + dy*dy + dz*dz + dw*dw;
  for (int m = 1; m < 64; m <<= 1) q += __shfl_xor(q, m);
  float rs = rsqrtf(q * (1.0f / 256.0f) + 1e-5f);
  int c0 = lane * 4;
  u16 h0 = f2bf(dx * rs * g[c0+0] + b[c0+0]);
  u16 h1 = f2bf(dy * rs * g[c0+1] + b[c0+1]);
  u16 h2 = f2bf(dz * rs * g[c0+2] + b[c0+2]);
  u16 h3 = f2bf(dw * rs * g[c0+3] + b[c0+3]);
  uint2 pk; pk.x = (u32)h0 | ((u32)h1 << 16); pk.y = (u32)h2 | ((u32)h3 << 16);
  *(uint2*)&out[(size_t)j * 256 + c0] = pk;
}

// ---------- final LN (f32 out) ----------
__global__ void __launch_bounds__(256) ln_final_kernel(const float* __restrict__ xin,
    const float* __restrict__ g, const float* __restrict__ b, float* __restrict__ out){
  int w = threadIdx.x >> 6, lane = threadIdx.x & 63;
  int j = blockIdx.x * 4 + w;
  float4 v = ((const float4*)xin)[(size_t)j * 64 + lane];
  float s = v.x + v.y + v.z + v.w;
  for (int m = 1; m < 64; m <<= 1) s += __shfl_xor(s, m);
  float mean = s * (1.0f / 256.0f);
  float dx = v.x - mean, dy = v.y - mean, dz = v.z - mean, dw = v.w - mean;
  float q = dx*dx + dy*dy + dz*dz + dw*dw;
  for (int m = 1; m < 64; m <<= 1) q += __shfl_xor(q, m);
  float rs = rsqrtf(q * (1.0f / 256.0f) + 1e-5f);
  int c0 = lane * 4;
  float4 o;
  o.x = dx * rs * g[c0+0] + b[c0+0];
  o.y = dy * rs * g[c0+1] + b[c0+1];
  o.z = dz * rs * g[c0+2] + b[c0+2];
  o.w = dw * rs * g[c0+3] + b[c0+3];
  ((float4*)out)[(size_t)j * 64 + lane] = o;
}

// ---------- GEMM: C[32768,Nn] = A[32768,K] @ Wt^T + bias (Wt is [Nn][K] bf16) ----------
// 128x128 tile, 4 waves (2x2), global_load_lds staging, XOR slot-swizzle.
// EPI 0: bf16 out. 1: gelu->bf16 out. 2 (proj): f32 out = res[gather(row)] + v.
// 3 (fc2): f32 out[scatter(row)] = res[row] + v.   (EPI 2/3 assume Nn outputs stride 256)
template<int EPI>
__global__ void __launch_bounds__(256) gemm_kernel(
    const u16* __restrict__ A, const u16* __restrict__ Wt,
    const float* __restrict__ bias, int K, int Nn,
    u16* __restrict__ outb, float* __restrict__ outf,
    const float* __restrict__ res, const u64* __restrict__ keys, int shift){
  __shared__ __align__(16) u16 As[128 * 32];
  __shared__ __align__(16) u16 Bs[128 * 32];
  int m0 = blockIdx.x * 128;
  int n0 = blockIdx.y * 128;
  int tid = threadIdx.x;
  int lane = tid & 63, lc = lane & 15, g = lane >> 4;
  int w = tid >> 6, wm = w >> 1, wn = w & 1;
  f32x4 acc[4][4];
  #pragma unroll
  for (int mi = 0; mi < 4; ++mi)
    #pragma unroll
    for (int ni = 0; ni < 4; ++ni) acc[mi][ni] = (f32x4){0.f,0.f,0.f,0.f};
  // staging: position p -> LDS 16B slot p (linear), content A[row=p>>2][(slot^((row>>1)&3))*8 ..]
  int r1 = tid >> 2, s1 = tid & 3;
  int p2 = tid + 256, r2 = p2 >> 2, s2 = p2 & 3;
  const u16* Ag1 = A  + (size_t)(m0 + r1) * K + (s1 ^ ((r1 >> 1) & 3)) * 8;
  const u16* Ag2 = A  + (size_t)(m0 + r2) * K + (s2 ^ ((r2 >> 1) & 3)) * 8;
  const u16* Bg1 = Wt + (size_t)(n0 + r1) * K + (s1 ^ ((r1 >> 1) & 3)) * 8;
  const u16* Bg2 = Wt + (size_t)(n0 + r2) * K + (s2 ^ ((r2 >> 1) & 3)) * 8;
  u16* Al1 = As + (tid & ~63) * 8;
  u16* Al2 = As + (tid & ~63) * 8 + 2048;
  u16* Bl1 = Bs + (tid & ~63) * 8;
  u16* Bl2 = Bs + (tid & ~63) * 8 + 2048;
  int fsw = (lc >> 1) & 3;   // read-side swizzle: row>>1 & 3 == lc>>1 & 3
  for (int kk = 0; kk < K; kk += 32){
    gload_lds16(Ag1 + kk, Al1);
    gload_lds16(Ag2 + kk, Al2);
    gload_lds16(Bg1 + kk, Bl1);
    gload_lds16(Bg2 + kk, Bl2);
    __syncthreads();
    bf16x8 af[4], bfr[4];
    #pragma unroll
    for (int mi = 0; mi < 4; ++mi)
      af[mi] = *(const bf16x8*)&As[(wm*64 + mi*16 + lc)*32 + (g ^ fsw)*8];
    #pragma unroll
    for (int ni = 0; ni < 4; ++ni)
      bfr[ni] = *(const bf16x8*)&Bs[(wn*64 + ni*16 + lc)*32 + (g ^ fsw)*8];
    #pragma unroll
    for (int mi = 0; mi < 4; ++mi)
      #pragma unroll
      for (int ni = 0; ni < 4; ++ni)
        acc[mi][ni] = mfma16(af[mi], bfr[ni], acc[mi][ni]);
    __syncthreads();
  }
  #pragma unroll
  for (int ni = 0; ni < 4; ++ni){
    int col = n0 + wn*64 + ni*16 + lc;
    float bv = bias[col];
    #pragma unroll
    for (int mi = 0; mi < 4; ++mi){
      #pragma unroll
      for (int r = 0; r < 4; ++r){
        int row = m0 + wm*64 + mi*16 + g*4 + r;
        float v = acc[mi][ni][r] + bv;
        if constexpr (EPI == 0){
          outb[(size_t)row * Nn + col] = f2bf(v);
        } else if constexpr (EPI == 1){
          outb[(size_t)row * Nn + col] = f2bf(gelu_tanh(v));
        } else if constexpr (EPI == 2){
          u32 src = rp_idx(keys, row, shift);
          outf[(size_t)row * 256 + col] = res[(size_t)src * 256 + col] + v;
        } else {
          u32 dst = rp_idx(keys, row, shift);
          outf[(size_t)dst * 256 + col] = res[(size_t)row * 256 + col] + v;
        }
      }
    }
  }
}

// ---------- attention: one block per (patch, head); chunked online softmax ----------
#define VSTR 516
#define ATTN_LDS (512*40*2 + 32*VSTR*2 + 512*4 + 4*16*40*2)
__global__ void __launch_bounds__(256) attn_kernel(
    const u16* __restrict__ qkvb, const float* __restrict__ dproj,
    u16* __restrict__ o){
  extern __shared__ char smem[];
  u16* Kl = (u16*)smem;                                   // [512][40]
  u16* Vt = (u16*)(smem + 512*40*2);                      // [32][VSTR] transposed V
  float* dl = (float*)(smem + 512*40*2 + 32*VSTR*2);      // [512]
  u16* Pl = (u16*)(smem + 512*40*2 + 32*VSTR*2 + 512*4);  // [4][16][40]
  int m = blockIdx.x >> 3;
  int h = blockIdx.x & 7;
  int base = m * 512;
  int tid = threadIdx.x, w = tid >> 6, lane = tid & 63, lc = lane & 15, g = lane >> 4;
  for (int i = tid; i < 512*4; i += 256){
    int row = i >> 2, ch = (i & 3) * 8;
    *(uint4*)&Kl[row*40 + ch] = *(const uint4*)&qkvb[(size_t)(base+row)*768 + 256 + h*32 + ch];
  }
  for (int i = tid; i < 512*4; i += 256){
    int row = i >> 2, d0 = (i & 3) * 8;
    uint4 vv = *(const uint4*)&qkvb[(size_t)(base+row)*768 + 512 + h*32 + d0];
    const u16* pv = (const u16*)&vv;
    #pragma unroll
    for (int e = 0; e < 8; ++e) Vt[(d0+e)*VSTR + row] = pv[e];
  }
  for (int i = tid; i < 512; i += 256) dl[i] = dproj[(size_t)(base+i)*8 + h];
  __syncthreads();
  u16* Pw = Pl + w * 640;
  const float SC = 0.17677669529663687f;  // 1/sqrt(32)
  const f32x4 zf = {0.f,0.f,0.f,0.f};
  for (int t = 0; t < 8; ++t){
    int q0 = w*128 + t*16;
    bf16x8 qf = *(const bf16x8*)&qkvb[(size_t)(base + q0 + lc)*768 + h*32 + g*8];
    f32x4 o0 = zf, o1 = zf;
    float m4[4] = {-1e30f,-1e30f,-1e30f,-1e30f};
    float l4[4] = {0.f,0.f,0.f,0.f};
    for (int c = 0; c < 4; ++c){
      int kb = c * 128;
      // --- scores for 128 keys: 8 MFMAs into registers ---
      f32x4 s[8];
      #pragma unroll
      for (int i = 0; i < 8; ++i){
        bf16x8 kf = *(const bf16x8*)&Kl[(kb + i*16 + lc)*40 + g*8];
        s[i] = mfma16(qf, kf, zf);
      }
      float dv[8];
      #pragma unroll
      for (int i = 0; i < 8; ++i) dv[i] = dl[kb + i*16 + lc];
      // --- one softmax update per 128 keys ---
      float sco[4];
      #pragma unroll
      for (int r = 0; r < 4; ++r){
        float a[8];
        #pragma unroll
        for (int i = 0; i < 8; ++i) a[i] = s[i][r]*SC - dv[i];
        float v = fmaxf(fmaxf(fmaxf(a[0],a[1]), fmaxf(a[2],a[3])),
                        fmaxf(fmaxf(a[4],a[5]), fmaxf(a[6],a[7])));
        v = fmaxf(v, __shfl_xor(v, 1));
        v = fmaxf(v, __shfl_xor(v, 2));
        v = fmaxf(v, __shfl_xor(v, 4));
        v = fmaxf(v, __shfl_xor(v, 8));
        float mn = fmaxf(m4[r], v);
        sco[r] = __expf(m4[r] - mn);
        m4[r] = mn;
        float rs = 0.f;
        #pragma unroll
        for (int i = 0; i < 8; ++i){
          float p = __expf(a[i] - mn);
          s[i][r] = p;
          rs += p;
        }
        rs += __shfl_xor(rs, 1);
        rs += __shfl_xor(rs, 2);
        rs += __shfl_xor(rs, 4);
        rs += __shfl_xor(rs, 8);
        l4[r] = l4[r]*sco[r] + rs;
      }
      #pragma unroll
      for (int r = 0; r < 4; ++r){ o0[r] *= sco[r]; o1[r] *= sco[r]; }
      // --- PV: 4 sub-blocks of 32 keys through LDS re-layout ---
      #pragma unroll
      for (int ii = 0; ii < 4; ++ii){
        int k2 = kb + ii*32;
        #pragma unroll
        for (int r = 0; r < 4; ++r){
          Pw[(g*4 + r)*40 + lc]      = f2bf(s[2*ii][r]);
          Pw[(g*4 + r)*40 + 16 + lc] = f2bf(s[2*ii+1][r]);
        }
        __threadfence_block();  // order P writes before re-layout read (wave-private)
        bf16x8 pf = *(const bf16x8*)&Pw[lc*40 + g*8];
        bf16x8 v0, v1;
        *(uint2*)&v0       = *(const uint2*)&Vt[lc*VSTR + k2 + g*8];
        *((uint2*)&v0 + 1) = *(const uint2*)&Vt[lc*VSTR + k2 + g*8 + 4];
        *(uint2*)&v1       = *(const uint2*)&Vt[(16+lc)*VSTR + k2 + g*8];
        *((uint2*)&v1 + 1) = *(const uint2*)&Vt[(16+lc)*VSTR + k2 + g*8 + 4];
        __threadfence_block();  // keep next P writes after these reads
        o0 = mfma16(pf, v0, o0);
        o1 = mfma16(pf, v1, o1);
      }
    }
    #pragma unroll
    for (int r = 0; r < 4; ++r){
      float inv = 1.0f / l4[r];
      size_t tok = (size_t)(base + q0 + g*4 + r);
      o[tok*256 + h*32 + lc]      = f2bf(o0[r] * inv);
      o[tok*256 + h*32 + 16 + lc] = f2bf(o1[r] * inv);
    }
  }
}

// ---------- host ----------
extern "C" void kernel_launch(void* const* d_in, const int* in_sizes, int n_in,
                              void* d_out, int out_size, void* d_ws, size_t ws_size,
                              hipStream_t stream){
  const float* x      = (const float*)d_in[0];
  const float* coords = (const float*)d_in[1];
  const float* ln1_g  = (const float*)d_in[2];
  const float* ln1_b  = (const float*)d_in[3];
  const float* w_qkv  = (const float*)d_in[4];
  const float* b_qkv  = (const float*)d_in[5];
  const float* w_proj = (const float*)d_in[6];
  const float* b_proj = (const float*)d_in[7];
  const float* w_pos  = (const float*)d_in[8];
  // d_in[9] = b_pos: cancels in softmax (row-constant), unused
  const float* ln2_g  = (const float*)d_in[10];
  const float* ln2_b  = (const float*)d_in[11];
  const float* w_fc1  = (const float*)d_in[12];
  const float* b_fc1  = (const float*)d_in[13];
  const float* w_fc2  = (const float*)d_in[14];
  const float* b_fc2  = (const float*)d_in[15];
  const float* norm_g = (const float*)d_in[16];
  const float* norm_b = (const float*)d_in[17];
  float* outp = (float*)d_out;

  char* ws = (char*)d_ws;
  size_t off = 0;
  auto alloc = [&](size_t bytes) -> void* {
    void* p = ws + off;
    off += (bytes + 255) & ~(size_t)255;
    return p;
  };
  u64*   keys   = (u64*)  alloc((size_t)2 * N_TOK * 8);     // both layers
  float* cmm    = (float*)alloc(256);
  float* dproj  = (float*)alloc((size_t)N_TOK * 8 * 4);
  u16*   h      = (u16*)  alloc((size_t)N_TOK * 256 * 2);   // also reused as h2
  u16*   qkvb   = (u16*)  alloc((size_t)N_TOK * 768 * 2);   // also reused as layer-2 output (f32)
  float* x2     = (float*)alloc((size_t)N_TOK * 256 * 4);
  u16*   t      = (u16*)  alloc((size_t)N_TOK * 1024 * 2);  // front 1/4 also reused as attn out o
  float* xA     = (float*)alloc((size_t)N_TOK * 256 * 4);
  u16*   wtqkv  = (u16*)  alloc((size_t)2 * 256 * 768 * 2);
  u16*   wtproj = (u16*)  alloc((size_t)2 * 256 * 256 * 2);
  u16*   wtfc1  = (u16*)  alloc((size_t)2 * 256 * 1024 * 2);
  u16*   wtfc2  = (u16*)  alloc((size_t)2 * 1024 * 256 * 2);
  u16*   o      = t;            // alias: o dead before fc1 writes t
  float* xB     = (float*)qkvb; // alias: layer-2 qkv dead before fc2 writes xB
  (void)in_sizes; (void)n_in; (void)out_size; (void)ws_size;

  minmax_kernel<<<1, 1024, 0, stream>>>(coords, cmm);
  wprep_kernel<<<dim3(8*24, 2),  256, 0, stream>>>(w_qkv,  wtqkv,  256, 768);
  wprep_kernel<<<dim3(8*8, 2),   256, 0, stream>>>(w_proj, wtproj, 256, 256);
  wprep_kernel<<<dim3(8*32, 2),  256, 0, stream>>>(w_fc1,  wtfc1,  256, 1024);
  wprep_kernel<<<dim3(32*8, 2),  256, 0, stream>>>(w_fc2,  wtfc2,  1024, 256);

  // both layers' sorts, batched
  codes_kernel<<<256, 256, 0, stream>>>(coords, cmm, keys);
  bitonic_local_sort<<<16, 256, 0, stream>>>(keys);
  for (int k = 8192; k <= 32768; k <<= 1){
    for (int j = k >> 1; j >= 4096; j >>= 1)
      bitonic_global_step<<<128, 256, 0, stream>>>(keys, j, k);
    bitonic_local_merge<<<16, 256, 0, stream>>>(keys, k);
  }

  for (int layer = 0; layer < 2; ++layer){
    int shift = (layer & 1) ? 256 : 0;
    const float* xin = (layer == 0) ? x : xA;
    float* xout = (layer == 0) ? xA : xB;
    u64* keyL = keys + (size_t)layer * N_TOK;

    gather_ln1_kernel<<<8192, 256, 0, stream>>>(xin, coords, keyL, shift,
        ln1_g + layer*256, ln1_b + layer*256, w_pos + layer*24, dproj, h);
    gemm_kernel<0><<<dim3(256, 6), 256, 0, stream>>>(h, wtqkv + (size_t)layer*768*256,
        b_qkv + layer*768, 256, 768, qkvb, nullptr, nullptr, nullptr, 0);
    attn_kernel<<<512, 256, ATTN_LDS, stream>>>(qkvb, dproj, o);
    gemm_kernel<2><<<dim3(256, 2), 256, 0, stream>>>(o, wtproj + (size_t)layer*256*256,
        b_proj + layer*256, 256, 256, nullptr, x2, xin, keyL, shift);
    ln_bf16_kernel<<<8192, 256, 0, stream>>>(x2, ln2_g + layer*256, ln2_b + layer*256, h);
    gemm_kernel<1><<<dim3(256, 8), 256, 0, stream>>>(h, wtfc1 + (size_t)layer*1024*256,
        b_fc1 + layer*1024, 256, 1024, t, nullptr, nullptr, nullptr, 0);
    gemm_kernel<3><<<dim3(256, 2), 256, 0, stream>>>(t, wtfc2 + (size_t)layer*256*1024,
        b_fc2 + layer*256, 1024, 256, nullptr, xout, x2, keyL, shift);
  }
  ln_final_kernel<<<8192, 256, 0, stream>>>(xB, norm_g, norm_b, outp);
}